// Round 3
// baseline (423.697 us; speedup 1.0000x reference)
//
#include <hip/hip_runtime.h>

// Problem constants (from the reference).
#define B_  64
#define T_  60
#define K_  3
#define S0_ 80
#define S1_ 80
#define BODY_ 85

#define BT_       (B_ * T_)                       // 3840 targets
#define GT_ELEMS  (B_ * K_ * S0_ * S1_ * BODY_)   // 104,448,000 floats
#define NO_ELEMS  (B_ * K_ * S0_ * S1_)           // 1,228,800 floats
#define TOTAL_ELEMS (GT_ELEMS + NO_ELEMS)         // 105,676,800 floats
#define GT_V4     (GT_ELEMS / 4)                  // 26,112,000 float4s (zeros)
#define TOTAL_V4  (TOTAL_ELEMS / 4)               // 26,419,200 float4s

// Fill config: 256 thr/block, 16 float4 per thread -> 4096 v4 (64 KB) per block.
// TOTAL_V4 / 4096 = 6450 blocks exactly; GT/no_obj boundary at block 6375 exactly,
// so every block writes a single uniform value (no per-element branch).
#define V4_PER_THREAD 16
#define V4_PER_BLOCK  (256 * V4_PER_THREAD)       // 4096
#define FILL_BLOCKS   (TOTAL_V4 / V4_PER_BLOCK)   // 6450 (exact)
#define GT_BLOCKS     (GT_V4 / V4_PER_BLOCK)      // 6375 (exact)

// ---------------------------------------------------------------------------
// Fill: zeros over ground_true, ones over no_obj_mask. 256 B per thread,
// block-contiguous coalesced stores. ~25 blocks/CU, enough to hit HBM write BW
// without being workgroup-dispatch-bound (R1/R2 lesson: 103K tiny WGs or the
// graph memset node both plateau at ~3.2 TB/s; rocclr-style shape hits 6.3).
// ---------------------------------------------------------------------------
__global__ __launch_bounds__(256) void yolo_fill_kernel(float4* __restrict__ out) {
    size_t base = (size_t)blockIdx.x * V4_PER_BLOCK + threadIdx.x;
    float v = (blockIdx.x < GT_BLOCKS) ? 0.0f : 1.0f;
    float4 vv = make_float4(v, v, v, v);
#pragma unroll
    for (int i = 0; i < V4_PER_THREAD; ++i)
        out[base + (size_t)i * 256] = vv;
}

// ---------------------------------------------------------------------------
// Scatter: one thread per (b, t) target. 3840 threads total.
// Matches XLA f32 arithmetic: no FP contraction, first-max argmax.
// ---------------------------------------------------------------------------
__global__ __launch_bounds__(256) void yolo_scatter_kernel(
        const float4* __restrict__ targets_xywh,  // (B,T,4) as float4
        const int*    __restrict__ target_cls,    // (B,T)
        const int*    __restrict__ valid,         // (B,T) bool -> int
        float*        __restrict__ out) {
#pragma clang fp contract(off)
    int idx = blockIdx.x * 256 + threadIdx.x;
    if (idx >= BT_) return;

    float4 t = targets_xywh[idx];
    float x = t.x * 80.0f;
    float y = t.y * 80.0f;
    float w = t.z * 80.0f;
    float h = t.w * 80.0f;

    // ANCHORS / STRIDE (stride = 8)
    const float aw[9] = {1.25f, 2.0f,  4.125f, 3.75f,  7.75f,  7.375f, 14.5f,  19.5f,  46.625f};
    const float ah[9] = {1.625f, 3.75f, 2.875f, 7.625f, 5.625f, 14.875f, 11.25f, 24.75f, 40.75f};

    int   best  = 0;
    float bestv = -1.0f;  // all ious >= 0, so anchor 0 always beats this
#pragma unroll
    for (int a = 0; a < 9; ++a) {
        float iw    = fminf(w, aw[a]);
        float ih    = fminf(h, ah[a]);
        float inter = iw * ih;
        inter       = fmaxf(inter, 0.0f);
        float uni   = w * h + aw[a] * ah[a] - inter;
        float iou   = inter / uni;
        if (iou > bestv) { bestv = iou; best = a; }  // strict > == first-max tiebreak
    }

    // in_scale = isin(best, {0,1,2}) & valid; otherwise the scatter drops.
    if (best >= K_) return;
    if (valid[idx] == 0) return;

    int b = idx / T_;
    int k = best;               // best % 3 == best here
    int i = (int)floorf(x);     // in [0,79] since t.x in [0,1)
    int j = (int)floorf(y);

    long gt_off = ((((long)b * K_ + k) * S0_ + j) * S1_ + i) * BODY_;
    float* p = out + gt_off;
    p[0] = x;
    p[1] = y;
    p[2] = w;
    p[3] = h;
    p[4] = 1.0f;
    p[5 + target_cls[idx]] = 1.0f;  // c = cls + 5, cls in [0,80)

    long no_off = (long)GT_ELEMS + (((long)b * K_ + k) * S0_ + j) * S1_ + i;
    out[no_off] = 0.0f;
}

extern "C" void kernel_launch(void* const* d_in, const int* in_sizes, int n_in,
                              void* d_out, int out_size, void* d_ws, size_t ws_size,
                              hipStream_t stream) {
    const float4* targets_xywh = (const float4*)d_in[0];
    const int*    target_cls   = (const int*)d_in[1];
    const int*    valid        = (const int*)d_in[2];
    float*        out          = (float*)d_out;

    // Single fill kernel: zeros (GT region) + ones (no_obj region).
    yolo_fill_kernel<<<FILL_BLOCKS, 256, 0, stream>>>((float4*)d_out);

    // Sparse target scatter (runs after fill in stream order).
    yolo_scatter_kernel<<<(BT_ + 255) / 256, 256, 0, stream>>>(
        targets_xywh, target_cls, valid, out);
}

// Round 4
// 401.430 us; speedup vs baseline: 1.0555x; 1.0555x over previous
//
#include <hip/hip_runtime.h>

// Problem constants (from the reference).
#define B_  64
#define T_  60
#define K_  3
#define S0_ 80
#define S1_ 80
#define BODY_ 85

#define BT_       (B_ * T_)                       // 3840 targets
#define GT_ELEMS  (B_ * K_ * S0_ * S1_ * BODY_)   // 104,448,000 floats
#define NO_ELEMS  (B_ * K_ * S0_ * S1_)           // 1,228,800 floats
#define TOTAL_ELEMS (GT_ELEMS + NO_ELEMS)         // 105,676,800 floats
#define GT_V4     (GT_ELEMS / 4)                  // 26,112,000 (exact)
#define TOTAL_V4  (TOTAL_ELEMS / 4)               // 26,419,200 (exact)

// ---------------------------------------------------------------------------
// Fill: ground_true region <- 0.0f, no_obj_mask region <- 1.0f.
// One float4 store per thread, fully coalesced. Measured best (R1: own-work
// ~66 us = ~6.4 TB/s). R3's 16-v4/thread 64KB-contiguous-block variant was
// ~25% slower; do not "optimize" this back.
// ---------------------------------------------------------------------------
__global__ __launch_bounds__(256) void yolo_fill_kernel(float4* __restrict__ out) {
    int idx = blockIdx.x * 256 + threadIdx.x;
    if (idx >= TOTAL_V4) return;
    float v = (idx < GT_V4) ? 0.0f : 1.0f;
    out[idx] = make_float4(v, v, v, v);
}

// ---------------------------------------------------------------------------
// Scatter: one thread per (b, t) target. 3840 threads total.
// Matches XLA f32 arithmetic: no FP contraction, first-max argmax.
// ---------------------------------------------------------------------------
__global__ __launch_bounds__(256) void yolo_scatter_kernel(
        const float4* __restrict__ targets_xywh,  // (B,T,4) as float4
        const int*    __restrict__ target_cls,    // (B,T)
        const int*    __restrict__ valid,         // (B,T) bool -> int
        float*        __restrict__ out) {
#pragma clang fp contract(off)
    int idx = blockIdx.x * 256 + threadIdx.x;
    if (idx >= BT_) return;

    float4 t = targets_xywh[idx];
    float x = t.x * 80.0f;
    float y = t.y * 80.0f;
    float w = t.z * 80.0f;
    float h = t.w * 80.0f;

    // ANCHORS / STRIDE (stride = 8)
    const float aw[9] = {1.25f, 2.0f,  4.125f, 3.75f,  7.75f,  7.375f, 14.5f,  19.5f,  46.625f};
    const float ah[9] = {1.625f, 3.75f, 2.875f, 7.625f, 5.625f, 14.875f, 11.25f, 24.75f, 40.75f};

    int   best  = 0;
    float bestv = -1.0f;  // all ious >= 0, so anchor 0 always beats this
#pragma unroll
    for (int a = 0; a < 9; ++a) {
        float iw    = fminf(w, aw[a]);
        float ih    = fminf(h, ah[a]);
        float inter = iw * ih;
        inter       = fmaxf(inter, 0.0f);
        float uni   = w * h + aw[a] * ah[a] - inter;
        float iou   = inter / uni;
        if (iou > bestv) { bestv = iou; best = a; }  // strict > == first-max tiebreak
    }

    // in_scale = isin(best, {0,1,2}) & valid; otherwise the scatter drops.
    if (best >= K_) return;
    if (valid[idx] == 0) return;

    int b = idx / T_;
    int k = best;               // best % 3 == best here
    int i = (int)floorf(x);     // in [0,79] since t.x in [0,1)
    int j = (int)floorf(y);

    long gt_off = ((((long)b * K_ + k) * S0_ + j) * S1_ + i) * BODY_;
    float* p = out + gt_off;
    p[0] = x;
    p[1] = y;
    p[2] = w;
    p[3] = h;
    p[4] = 1.0f;
    p[5 + target_cls[idx]] = 1.0f;  // c = cls + 5, cls in [0,80)

    long no_off = (long)GT_ELEMS + (((long)b * K_ + k) * S0_ + j) * S1_ + i;
    out[no_off] = 0.0f;
}

extern "C" void kernel_launch(void* const* d_in, const int* in_sizes, int n_in,
                              void* d_out, int out_size, void* d_ws, size_t ws_size,
                              hipStream_t stream) {
    const float4* targets_xywh = (const float4*)d_in[0];
    const int*    target_cls   = (const int*)d_in[1];
    const int*    valid        = (const int*)d_in[2];
    float*        out          = (float*)d_out;

    int fill_blocks = (TOTAL_V4 + 255) / 256;   // 103,200 blocks
    yolo_fill_kernel<<<fill_blocks, 256, 0, stream>>>((float4*)d_out);

    int scat_blocks = (BT_ + 255) / 256;        // 15 blocks
    yolo_scatter_kernel<<<scat_blocks, 256, 0, stream>>>(
        targets_xywh, target_cls, valid, out);
}